// Round 11
// baseline (43.581 us; speedup 1.0000x reference)
//
#include <hip/hip_runtime.h>

#define TT 1024
#define FF 512
#define BB 32
#define MAXSEG 513   // valleys are never adjacent -> cnt <= 512

typedef float f32x4 __attribute__((ext_vector_type(4)));

__device__ __forceinline__ void nt_store4(float* p, f32x4 v) {
    __builtin_nontemporal_store(v, (f32x4*)p);
}

// ---------------- Kernel 1: ws[b,t] = sigmoid(x[b,t,:] . w + bias) ----------
// One wave per row; lane i handles 8 contiguous floats. Double accumulation:
// closest-to-exact dot -> minimizes strict-< valley tie flips vs numpy ref.
// At the 64 MB cold-read HBM floor (~10 us). PROVEN — do not touch.
__global__ __launch_bounds__(256) void gate_kernel(const float* __restrict__ x,
                                                   const float* __restrict__ w,
                                                   const float* __restrict__ bias,
                                                   float* __restrict__ ws) {
    int wid  = threadIdx.x >> 6;
    int lane = threadIdx.x & 63;
    int row  = blockIdx.x * 4 + wid;              // 0 .. 32767
    const float4* xr = (const float4*)(x + (size_t)row * FF);
    const float4* wr = (const float4*)w;
    float4 x0 = xr[lane * 2],     x1 = xr[lane * 2 + 1];
    float4 w0 = wr[lane * 2],     w1 = wr[lane * 2 + 1];
    double acc = (double)x0.x * w0.x + (double)x0.y * w0.y +
                 (double)x0.z * w0.z + (double)x0.w * w0.w +
                 (double)x1.x * w1.x + (double)x1.y * w1.y +
                 (double)x1.z * w1.z + (double)x1.w * w1.w;
    #pragma unroll
    for (int off = 32; off; off >>= 1) acc += __shfl_down(acc, off);
    if (lane == 0) {
        float z = (float)acc + bias[0];
        ws[row] = 1.0f / (1.0f + expf(-z));
    }
}

// ------- Kernel 2: seg build (32 blocks) + upper-half zero-fill (1024) ------
// seg is LATENCY-bound (3.5 us, ~0 BW) -> overlap the unconditional 32 MB
// zero-fill of out rows s in [512,1024) (counts<=512 always) with its idle
// bandwidth window. zfill blocks touch no LDS/barriers (block-uniform exit).
__global__ __launch_bounds__(1024) void seg_zfill_kernel(const float* __restrict__ ws,
                                                         int* __restrict__ seg_start,
                                                         int* __restrict__ seg_end,
                                                         float* __restrict__ den,
                                                         int* __restrict__ counts,
                                                         float* __restrict__ out) {
    int bid = blockIdx.x;
    int t   = threadIdx.x;

    if (bid >= BB) {                       // ---- zero-fill path (1024 blocks)
        int idx  = bid - BB;               // 0 .. 1023
        int u    = idx * 16 + (t >> 6);    // upper-row index, 0 .. 16383
        int lane = t & 63;
        int b    = u >> 9;
        int s    = 512 + (u & 511);
        float* orow = out + ((size_t)b * TT + s) * FF + lane * 8;
        f32x4 z = 0.0f;
        nt_store4(orow, z);
        nt_store4(orow + 4, z);
        return;
    }

    int b = bid;                           // ---- seg path (PROVEN, verbatim)
    __shared__ float w[TT];
    __shared__ float p[TT];
    __shared__ unsigned long long words[16];
    __shared__ float wavesum[16];
    __shared__ int sst[MAXSEG];
    __shared__ int sen[MAXSEG];

    w[t] = ws[b * TT + t];
    __syncthreads();

    float wt = w[t];
    bool valley = (t > 0) && (t < TT - 1) && (wt < w[t - 1]) && (wt < w[t + 1]);
    unsigned long long m = __ballot(valley);
    int wid = t >> 6, lane = t & 63;
    if (lane == 0) words[wid] = m;

    float s = wt;
    #pragma unroll
    for (int off = 1; off < 64; off <<= 1) {
        float v = __shfl_up(s, off);
        if (lane >= off) s += v;
    }
    if (lane == 63) wavesum[wid] = s;
    __syncthreads();

    float offset = 0.0f;
    for (int i = 0; i < wid; ++i) offset += wavesum[i];
    p[t] = s + offset;                     // inclusive prefix over the row

    int before = __popcll(m & ((1ull << lane) - 1ull));
    int total = 0;
    for (int i = 0; i < 16; ++i) {
        int pc = __popcll(words[i]);
        if (i < wid) before += pc;
        total += pc;
    }
    if (valley) {
        int en = t + 2; if (en > TT) en = TT;
        sst[before + 1] = t;               // start of segment rank+1
        sen[before]     = en;              // end of segment rank
    }
    if (t == 0) {
        sst[0]     = 0;
        sen[total] = TT;
        counts[b]  = total + 1;
    }
    __syncthreads();

    int cnt = total + 1;
    if (t < cnt) {
        int st = sst[t], en = sen[t];
        seg_start[b * TT + t] = st;
        seg_end  [b * TT + t] = en;
        float d = p[en - 1] - (st > 0 ? p[st - 1] : 0.0f);
        den[b * TT + t] = fmaxf(d, 1e-6f);
    }
}

// ------- Kernel 3: out[b,s<512,:] = sum_t ws*x / den  (+ mask) --------------
// R4's proven per-wave structure, restricted to the lower half (upper half
// pre-zeroed by kernel 2). XCD-swizzled; 8-row clamped unroll; nt stores.
__global__ __launch_bounds__(256) void out_kernel(const float* __restrict__ x,
                                                  const float* __restrict__ ws,
                                                  const int* __restrict__ seg_start,
                                                  const int* __restrict__ seg_end,
                                                  const float* __restrict__ den,
                                                  const int* __restrict__ counts,
                                                  const int* __restrict__ seq,
                                                  float* __restrict__ out) {
    int bid = blockIdx.x;

    // ---- fused new_mask: 32 designated blocks write the [B,T] mask
    if ((bid & 127) == 0) {
        int bb = bid >> 7;
        int maxc = 0;
        #pragma unroll
        for (int i = 0; i < BB; ++i) maxc = max(maxc, counts[i]);
        float l0 = (float)seq[0];
        float v  = ((float)seq[bb] / l0) * (float)maxc;   // match jnp f32 order
        int nl = (int)v;                                  // trunc like astype
        float* mrow = out + (size_t)BB * TT * FF + (size_t)bb * TT;
        int s4 = threadIdx.x * 4;
        f32x4 mv;
        mv.x = (s4 + 0 < nl) ? 1.0f : 0.0f;
        mv.y = (s4 + 1 < nl) ? 1.0f : 0.0f;
        mv.z = (s4 + 2 < nl) ? 1.0f : 0.0f;
        mv.w = (s4 + 3 < nl) ? 1.0f : 0.0f;
        nt_store4(mrow + s4, mv);
    }

    // XCD-aware bijective swizzle: 4096 blocks = 8 x 512 -> XCD k owns the
    // lower halves of 4 contiguous batches.
    int swz = (bid & 7) * 512 + (bid >> 3);

    int wid  = threadIdx.x >> 6;
    int lane = threadIdx.x & 63;
    int rr = swz * 4 + wid;               // 0 .. 16383
    int b  = rr >> 9;
    int s  = rr & 511;
    int bs = b * TT + s;
    float* orow = out + (size_t)bs * FF + lane * 8;
    if (s >= counts[b]) {                 // dead rows below 512
        f32x4 z = 0.0f;
        nt_store4(orow, z);
        nt_store4(orow + 4, z);
        return;
    }
    int st = seg_start[bs], en = seg_end[bs];
    float inv = 1.0f / den[bs];
    const float* xb  = x + (size_t)b * TT * FF + lane * 8;
    const float* wsr = ws + b * TT;
    f32x4 a0 = 0.0f, a1 = 0.0f;
    // 8-row predicated unroll: all 16 loads independent, issued up front.
    #pragma unroll
    for (int k = 0; k < 8; ++k) {
        int t  = st + k;
        int tc = t < en ? t : en - 1;     // clamp: safe re-read, L1-hit
        float wt = t < en ? wsr[tc] : 0.0f;
        const f32x4* xr = (const f32x4*)(xb + (size_t)tc * FF);
        a0 += wt * xr[0];
        a1 += wt * xr[1];
    }
    // rare tail (len > 8)
    for (int t = st + 8; t < en; ++t) {
        float wt = wsr[t];
        const f32x4* xr = (const f32x4*)(xb + (size_t)t * FF);
        a0 += wt * xr[0];
        a1 += wt * xr[1];
    }
    nt_store4(orow,     a0 * inv);
    nt_store4(orow + 4, a1 * inv);
}

extern "C" void kernel_launch(void* const* d_in, const int* in_sizes, int n_in,
                              void* d_out, int out_size, void* d_ws, size_t ws_size,
                              hipStream_t stream) {
    const float* x    = (const float*)d_in[0];
    const float* aw   = (const float*)d_in[1];
    const float* ab   = (const float*)d_in[2];
    const int*   seq  = (const int*)d_in[3];
    float* out = (float*)d_out;

    // workspace layout (floats): ws[32768] | den[32768] | sstart[32768] |
    //                            send[32768] | counts[32]
    float* ws     = (float*)d_ws;
    float* den    = ws + BB * TT;
    int*   sstart = (int*)(ws + 2 * BB * TT);
    int*   send   = (int*)(ws + 3 * BB * TT);
    int*   counts = (int*)(ws + 4 * BB * TT);

    gate_kernel<<<BB * TT / 4, 256, 0, stream>>>(x, aw, ab, ws);
    seg_zfill_kernel<<<BB + 1024, 1024, 0, stream>>>(ws, sstart, send, den,
                                                     counts, out);
    out_kernel<<<4096, 256, 0, stream>>>(x, ws, sstart, send, den, counts,
                                         seq, out);
}

// Round 12
// 40.477 us; speedup vs baseline: 1.0767x; 1.0767x over previous
//
#include <hip/hip_runtime.h>

#define TT 1024
#define FF 512
#define BB 32
#define MAXSEG 513   // valleys are never adjacent -> cnt <= 512

typedef float f32x4 __attribute__((ext_vector_type(4)));

__device__ __forceinline__ void nt_store4(float* p, f32x4 v) {
    __builtin_nontemporal_store(v, (f32x4*)p);
}

// ---------------- Kernel 1: ws[b,t] = sigmoid(x[b,t,:] . w + bias) ----------
// One wave per row; lane i handles 8 contiguous floats. Double accumulation:
// closest-to-exact dot -> minimizes strict-< valley tie flips vs numpy ref.
// At the 64 MB cold-read HBM floor (~10 us). PROVEN — do not touch.
__global__ __launch_bounds__(256) void gate_kernel(const float* __restrict__ x,
                                                   const float* __restrict__ w,
                                                   const float* __restrict__ bias,
                                                   float* __restrict__ ws) {
    int wid  = threadIdx.x >> 6;
    int lane = threadIdx.x & 63;
    int row  = blockIdx.x * 4 + wid;              // 0 .. 32767
    const float4* xr = (const float4*)(x + (size_t)row * FF);
    const float4* wr = (const float4*)w;
    float4 x0 = xr[lane * 2],     x1 = xr[lane * 2 + 1];
    float4 w0 = wr[lane * 2],     w1 = wr[lane * 2 + 1];
    double acc = (double)x0.x * w0.x + (double)x0.y * w0.y +
                 (double)x0.z * w0.z + (double)x0.w * w0.w +
                 (double)x1.x * w1.x + (double)x1.y * w1.y +
                 (double)x1.z * w1.z + (double)x1.w * w1.w;
    #pragma unroll
    for (int off = 32; off; off >>= 1) acc += __shfl_down(acc, off);
    if (lane == 0) {
        float z = (float)acc + bias[0];
        ws[row] = 1.0f / (1.0f + expf(-z));
    }
}

// ---------------- Kernel 2: per-batch valley detect + segment build ---------
// 32 blocks x 1024 threads; fully parallel rank/prefix construction. ~3.5 us
// (latency-bound, small). PROVEN.
__global__ __launch_bounds__(1024) void seg_kernel(const float* __restrict__ ws,
                                                   int* __restrict__ seg_start,
                                                   int* __restrict__ seg_end,
                                                   float* __restrict__ den,
                                                   int* __restrict__ counts) {
    int b = blockIdx.x, t = threadIdx.x;
    __shared__ float w[TT];
    __shared__ float p[TT];
    __shared__ unsigned long long words[16];
    __shared__ float wavesum[16];
    __shared__ int sst[MAXSEG];
    __shared__ int sen[MAXSEG];

    w[t] = ws[b * TT + t];
    __syncthreads();

    float wt = w[t];
    bool valley = (t > 0) && (t < TT - 1) && (wt < w[t - 1]) && (wt < w[t + 1]);
    unsigned long long m = __ballot(valley);
    int wid = t >> 6, lane = t & 63;
    if (lane == 0) words[wid] = m;

    float s = wt;
    #pragma unroll
    for (int off = 1; off < 64; off <<= 1) {
        float v = __shfl_up(s, off);
        if (lane >= off) s += v;
    }
    if (lane == 63) wavesum[wid] = s;
    __syncthreads();

    float offset = 0.0f;
    for (int i = 0; i < wid; ++i) offset += wavesum[i];
    p[t] = s + offset;                     // inclusive prefix over the row

    int before = __popcll(m & ((1ull << lane) - 1ull));
    int total = 0;
    for (int i = 0; i < 16; ++i) {
        int pc = __popcll(words[i]);
        if (i < wid) before += pc;
        total += pc;
    }
    if (valley) {
        int en = t + 2; if (en > TT) en = TT;
        sst[before + 1] = t;               // start of segment rank+1
        sen[before]     = en;              // end of segment rank
    }
    if (t == 0) {
        sst[0]     = 0;
        sen[total] = TT;
        counts[b]  = total + 1;
    }
    __syncthreads();

    int cnt = total + 1;
    if (t < cnt) {
        int st = sst[t], en = sen[t];
        seg_start[b * TT + t] = st;
        seg_end  [b * TT + t] = en;
        float d = p[en - 1] - (st > 0 ? p[st - 1] : 0.0f);
        den[b * TT + t] = fmaxf(d, 1e-6f);
    }
}

// ---------------- Kernel 3: out[b,s,:] = sum_t ws*x / den  (+ mask) ---------
// One wave per output row; XCD-swizzled blocks; branch-free 8-row predicated
// unroll (16 loads in flight); nontemporal stores. R4-exact. PROVEN 40.3 us.
__global__ __launch_bounds__(256) void out_kernel(const float* __restrict__ x,
                                                  const float* __restrict__ ws,
                                                  const int* __restrict__ seg_start,
                                                  const int* __restrict__ seg_end,
                                                  const float* __restrict__ den,
                                                  const int* __restrict__ counts,
                                                  const int* __restrict__ seq,
                                                  float* __restrict__ out) {
    int bid = blockIdx.x;

    // ---- fused new_mask: 32 designated blocks write the [B,T] mask
    if ((bid & 255) == 0) {
        int bb = bid >> 8;
        int maxc = 0;
        #pragma unroll
        for (int i = 0; i < BB; ++i) maxc = max(maxc, counts[i]);
        float l0 = (float)seq[0];
        float v  = ((float)seq[bb] / l0) * (float)maxc;   // match jnp f32 order
        int nl = (int)v;                                  // trunc like astype
        float* mrow = out + (size_t)BB * TT * FF + (size_t)bb * TT;
        int s4 = threadIdx.x * 4;
        f32x4 mv;
        mv.x = (s4 + 0 < nl) ? 1.0f : 0.0f;
        mv.y = (s4 + 1 < nl) ? 1.0f : 0.0f;
        mv.z = (s4 + 2 < nl) ? 1.0f : 0.0f;
        mv.w = (s4 + 3 < nl) ? 1.0f : 0.0f;
        nt_store4(mrow + s4, mv);
    }

    // XCD-aware bijective swizzle: 8192 blocks, 8 XCDs -> XCD k gets the
    // contiguous swz range [k*1024, (k+1)*1024) = 4 batches (8 MB window).
    int swz = (bid & 7) * 1024 + (bid >> 3);

    int wid  = threadIdx.x >> 6;
    int lane = threadIdx.x & 63;
    int bs = swz * 4 + wid;               // b*1024 + s
    int b  = bs >> 10;
    int s  = bs & 1023;
    float* orow = out + (size_t)bs * FF + lane * 8;
    if (s >= counts[b]) {                 // zero-filled unused segment rows
        f32x4 z = 0.0f;
        nt_store4(orow, z);
        nt_store4(orow + 4, z);
        return;
    }
    int st = seg_start[bs], en = seg_end[bs];
    float inv = 1.0f / den[bs];
    const float* xb  = x + (size_t)b * TT * FF + lane * 8;
    const float* wsr = ws + b * TT;
    f32x4 a0 = 0.0f, a1 = 0.0f;
    // 8-row predicated unroll: all 16 loads independent, issued up front.
    #pragma unroll
    for (int k = 0; k < 8; ++k) {
        int t  = st + k;
        int tc = t < en ? t : en - 1;     // clamp: safe re-read, L1-hit
        float wt = t < en ? wsr[tc] : 0.0f;
        const f32x4* xr = (const f32x4*)(xb + (size_t)tc * FF);
        a0 += wt * xr[0];
        a1 += wt * xr[1];
    }
    // rare tail (len > 8)
    for (int t = st + 8; t < en; ++t) {
        float wt = wsr[t];
        const f32x4* xr = (const f32x4*)(xb + (size_t)t * FF);
        a0 += wt * xr[0];
        a1 += wt * xr[1];
    }
    nt_store4(orow,     a0 * inv);
    nt_store4(orow + 4, a1 * inv);
}

extern "C" void kernel_launch(void* const* d_in, const int* in_sizes, int n_in,
                              void* d_out, int out_size, void* d_ws, size_t ws_size,
                              hipStream_t stream) {
    const float* x    = (const float*)d_in[0];
    const float* aw   = (const float*)d_in[1];
    const float* ab   = (const float*)d_in[2];
    const int*   seq  = (const int*)d_in[3];
    float* out = (float*)d_out;

    // workspace layout (floats): ws[32768] | den[32768] | sstart[32768] |
    //                            send[32768] | counts[32]
    float* ws     = (float*)d_ws;
    float* den    = ws + BB * TT;
    int*   sstart = (int*)(ws + 2 * BB * TT);
    int*   send   = (int*)(ws + 3 * BB * TT);
    int*   counts = (int*)(ws + 4 * BB * TT);

    gate_kernel<<<BB * TT / 4, 256, 0, stream>>>(x, aw, ab, ws);
    seg_kernel<<<BB, 1024, 0, stream>>>(ws, sstart, send, den, counts);
    out_kernel<<<BB * TT / 4, 256, 0, stream>>>(x, ws, sstart, send, den, counts,
                                                seq, out);
}